// Round 16
// baseline (1660.338 us; speedup 1.0000x reference)
//
#include <hip/hip_runtime.h>
#include <hip/hip_bf16.h>

// ---------------------------------------------------------------------------
// SpatialGATEncoder: 4-layer GATv2, N=100k, E=800k, HID=128, H=4, D=32.
// Round 19 = R18 (1523us measured) + ONE change:
//  - edge_score: 2 tiles (128 edges) per block, cross-tile pipelined.
//    Tile-B gathers + seattr issued between tile-A's transpose barrier and
//    tile-A phase 2 (gather latency hides under A's VALU); B's MFMA runs
//    before the barrier A's readers need. pw/att staged once; 6250 blocks.
//  - Everything else byte-identical to R18 (hierarchical scan, pre-exp'd
//    scores, 4-way aggregate).
// ---------------------------------------------------------------------------

using bf16x8 = __attribute__((ext_vector_type(8))) short;
using f32x4  = __attribute__((ext_vector_type(4))) float;

__device__ inline unsigned short f2bf(float x) {
  __hip_bfloat16 h = __float2bfloat16(x);
  return *reinterpret_cast<unsigned short*>(&h);
}
__device__ inline float bf2f(unsigned short u) {
  unsigned int x = ((unsigned int)u) << 16;
  return __uint_as_float(x);
}

// ---------------- CSR build ----------------
__global__ __launch_bounds__(256) void count_kernel(const int* __restrict__ dstv,
                                                    int* __restrict__ deg, int E) {
  int e = blockIdx.x * 256 + threadIdx.x;
  if (e < E) atomicAdd(&deg[dstv[e]], 1);
}

// hierarchical scan, stage 1: per-block exclusive scan of 1024 elems
__global__ __launch_bounds__(1024) void scan_local_kernel(
    const int* __restrict__ deg, int* __restrict__ off,
    int* __restrict__ bsum, int n) {
  __shared__ int wsum[16];
  int t = threadIdx.x;
  int lane = t & 63, wid = t >> 6;
  int i = blockIdx.x * 1024 + t;
  int v = (i < n) ? deg[i] : 0;
  int x = v;
  #pragma unroll
  for (int o = 1; o < 64; o <<= 1) {
    int y = __shfl_up(x, o, 64);
    if (lane >= o) x += y;
  }
  if (lane == 63) wsum[wid] = x;
  __syncthreads();
  if (wid == 0) {
    int w = (lane < 16) ? wsum[lane] : 0;
    #pragma unroll
    for (int o = 1; o < 16; o <<= 1) {
      int y = __shfl_up(w, o, 64);
      if (lane >= o) w += y;
    }
    if (lane < 16) wsum[lane] = w;
  }
  __syncthreads();
  int wbase = (wid == 0) ? 0 : wsum[wid - 1];
  if (i < n) off[i] = wbase + (x - v);
  if (t == 0) bsum[blockIdx.x] = wsum[15];
}

// stage 2: single-block scan of the <=1024 block sums; writes off[n] = total
__global__ __launch_bounds__(1024) void scan_bsums_kernel(
    const int* __restrict__ bsum, int* __restrict__ bpre,
    int nb, int* __restrict__ off, int n) {
  __shared__ int wsum[16];
  int t = threadIdx.x;
  int lane = t & 63, wid = t >> 6;
  int v = (t < nb) ? bsum[t] : 0;
  int x = v;
  #pragma unroll
  for (int o = 1; o < 64; o <<= 1) {
    int y = __shfl_up(x, o, 64);
    if (lane >= o) x += y;
  }
  if (lane == 63) wsum[wid] = x;
  __syncthreads();
  if (wid == 0) {
    int w = (lane < 16) ? wsum[lane] : 0;
    #pragma unroll
    for (int o = 1; o < 16; o <<= 1) {
      int y = __shfl_up(w, o, 64);
      if (lane >= o) w += y;
    }
    if (lane < 16) wsum[lane] = w;
  }
  __syncthreads();
  int wbase = (wid == 0) ? 0 : wsum[wid - 1];
  if (t < nb) bpre[t] = wbase + (x - v);
  if (t == 0) off[n] = wsum[15];
}

// stage 3: add block prefix back; copy to cursor
__global__ __launch_bounds__(256) void scan_addback_kernel(
    int* __restrict__ off, const int* __restrict__ bpre,
    int* __restrict__ cursor, int n) {
  int i = blockIdx.x * 256 + threadIdx.x;
  if (i < n) {
    int v = off[i] + bpre[i >> 10];
    off[i] = v;
    cursor[i] = v;
  }
}

// sort edges by dst: ssrc/sdst/seattr in segment order
__global__ __launch_bounds__(256) void place_kernel(const int* __restrict__ srcv,
                                                    const int* __restrict__ dstv,
                                                    const float* __restrict__ eattr,
                                                    int* __restrict__ cursor,
                                                    int* __restrict__ ssrc,
                                                    int* __restrict__ sdst,
                                                    float* __restrict__ seattr, int E) {
  int e = blockIdx.x * 256 + threadIdx.x;
  if (e < E) {
    int d = dstv[e];
    int p = atomicAdd(&cursor[d], 1);
    ssrc[p] = srcv[e];
    sdst[p] = d;
    seattr[p * 3 + 0] = eattr[e * 3 + 0];
    seattr[p * 3 + 1] = eattr[e * 3 + 1];
    seattr[p * 3 + 2] = eattr[e * 3 + 2];
  }
}

// ---------------- weight transpose f32 -> bf16, WT[n][k] = W[k][n] ----------------
// 10 blocks: 0..3 We (l0 + 3), 4..6 Wl, 7..9 Wr
__global__ __launch_bounds__(256) void wt_kernel(
    const float* __restrict__ l0_We, const float* __restrict__ We,
    const float* __restrict__ Wl, const float* __restrict__ Wr,
    unsigned short* __restrict__ WeT, unsigned short* __restrict__ WlT,
    unsigned short* __restrict__ WrT) {
  int b = blockIdx.x, t = threadIdx.x;
  const float* src;
  unsigned short* dst;
  if (b == 0)      { src = l0_We;              dst = WeT; }
  else if (b < 4)  { src = We + (b - 1) * 16384; dst = WeT + b * 16384; }
  else if (b < 7)  { src = Wl + (b - 4) * 16384; dst = WlT + (b - 4) * 16384; }
  else             { src = Wr + (b - 7) * 16384; dst = WrT + (b - 7) * 16384; }
  int n = t >> 1, k0 = (t & 1) * 64;
  #pragma unroll
  for (int k = 0; k < 64; ++k)
    dst[n * 128 + k0 + k] = f2bf(src[(k0 + k) * 128 + n]);
}

// ---------------- layer-0 node projection (K = 12) -> bf16 ----------------
__global__ __launch_bounds__(256) void node_proj0_kernel(
    const float* __restrict__ x,
    const float* __restrict__ Wl, const float* __restrict__ bl,
    const float* __restrict__ Wr, const float* __restrict__ br,
    unsigned short* __restrict__ xl, unsigned short* __restrict__ xr, int N) {
  int idx = blockIdx.x * 256 + threadIdx.x;
  int node = idx >> 7, col = idx & 127;
  if (node >= N) return;
  float al = bl[col], ar = br[col];
  const float* xrow = x + node * 12;
  #pragma unroll
  for (int k = 0; k < 12; ++k) {
    float xv = xrow[k];
    al += xv * Wl[k * 128 + col];
    ar += xv * Wr[k * 128 + col];
  }
  xl[idx] = f2bf(al);
  xr[idx] = f2bf(ar);
}

// ---------------- node projection MFMA: xl = h@Wl+bl, xr = h@Wr+br (bf16) ----------------
__global__ __launch_bounds__(256) void node_proj_kernel(
    const unsigned short* __restrict__ hbf,
    const unsigned short* __restrict__ WlT, const float* __restrict__ bl,
    const unsigned short* __restrict__ WrT, const float* __restrict__ br,
    unsigned short* __restrict__ xl, unsigned short* __restrict__ xr, int N) {
  __shared__ unsigned short A_sh[64 * 136];
  int t = threadIdx.x;
  int nb = blockIdx.x * 64;
  #pragma unroll
  for (int it = 0; it < 4; ++it) {
    int idx = it * 256 + t;
    int row = idx >> 4, chunk = idx & 15;
    int ng = nb + row;
    float4 v = make_float4(0.f, 0.f, 0.f, 0.f);
    if (ng < N) v = *(const float4*)(hbf + ng * 128 + chunk * 8);
    *(float4*)(A_sh + row * 136 + chunk * 8) = v;
  }
  __syncthreads();
  int lane = t & 63, w = t >> 6;
  int m = lane & 15, quad = lane >> 4;
  bf16x8 afr[4];
  #pragma unroll
  for (int s = 0; s < 4; ++s)
    afr[s] = *(const bf16x8*)(A_sh + (w * 16 + m) * 136 + s * 32 + quad * 8);
  #pragma unroll
  for (int part = 0; part < 2; ++part) {
    const unsigned short* Bt = part ? WrT : WlT;
    const float* bias = part ? br : bl;
    unsigned short* out = part ? xr : xl;
    f32x4 acc[8];
    #pragma unroll
    for (int tt = 0; tt < 8; ++tt)
      #pragma unroll
      for (int r = 0; r < 4; ++r) acc[tt][r] = 0.f;
    #pragma unroll
    for (int tt = 0; tt < 8; ++tt)
      #pragma unroll
      for (int s = 0; s < 4; ++s) {
        bf16x8 b = *(const bf16x8*)(Bt + (tt * 16 + m) * 128 + s * 32 + quad * 8);
        acc[tt] = __builtin_amdgcn_mfma_f32_16x16x32_bf16(afr[s], b, acc[tt], 0, 0, 0);
      }
    #pragma unroll
    for (int tt = 0; tt < 8; ++tt) {
      int col = tt * 16 + m;
      float bv = bias[col];
      #pragma unroll
      for (int r = 0; r < 4; ++r) {
        int ng = nb + w * 16 + quad * 4 + r;
        if (ng < N) out[ng * 128 + col] = f2bf(acc[tt][r] + bv);
      }
    }
  }
}

// ---------------- edge-score: 2 tiles/block, cross-tile pipelined ------------
// scores[] stores w = exp(sc) (max-free softmax, validated since R13).
__global__ __launch_bounds__(256) void edge_score_kernel(
    const float* __restrict__ seattr,  // E x 3 (sorted)
    const float* __restrict__ Pw,      // 3 x 128
    const float* __restrict__ Pb,      // 128
    const unsigned short* __restrict__ WeT,  // 128 x 128 bf16 [n][k]
    const float* __restrict__ attw,    // 128
    const unsigned short* __restrict__ xl, const unsigned short* __restrict__ xr,
    const int* __restrict__ ssrc, const int* __restrict__ sdst,
    float* __restrict__ scores, int E) {
  __shared__ unsigned short ee_sh[64 * 128];  // 16 KB, XOR-swizzled 16B chunks
  __shared__ float att_sh[4 * 40];            // head-major, stride 40
  __shared__ float pw_sh[512];                // Pw rows 0..2 then Pb
  int t = threadIdx.x;
  int eb = blockIdx.x * 128;                  // two 64-edge tiles
  int lane = t & 63, w = t >> 6;
  int m = lane & 15, quad = lane >> 4;

  if (t < 128) att_sh[(t >> 5) * 40 + (t & 31)] = attw[t];
  for (int i = t; i < 512; i += 256) pw_sh[i] = (i < 384) ? Pw[i] : Pb[i - 384];

  int le2 = t >> 2, hh = t & 3;

  // ---- tile A gathers (T14 hoist)
  int egA = eb + le2;
  int svA = 0, dvA = 0;
  if (egA < E) { svA = ssrc[egA]; dvA = sdst[egA]; }
  bf16x8 xaA[4], xbA[4];
  #pragma unroll
  for (int j = 0; j < 4; ++j) {
    xaA[j] = *(const bf16x8*)(xl + (size_t)svA * 128 + hh * 32 + j * 8);
    xbA[j] = *(const bf16x8*)(xr + (size_t)dvA * 128 + hh * 32 + j * 8);
  }
  __builtin_amdgcn_sched_barrier(0);
  __syncthreads();  // pw_sh / att_sh ready

  // ---- tile A phase 1
  int eA = eb + w * 16 + m;
  float a0 = 0.f, a1 = 0.f, a2 = 0.f;
  if (eA < E) { a0 = seattr[eA * 3]; a1 = seattr[eA * 3 + 1]; a2 = seattr[eA * 3 + 2]; }
  bf16x8 afr[4];
  #pragma unroll
  for (int s = 0; s < 4; ++s) {
    int k0 = s * 32 + quad * 8;
    f32x4 r0a = *(const f32x4*)(pw_sh + k0),       r0b = *(const f32x4*)(pw_sh + k0 + 4);
    f32x4 r1a = *(const f32x4*)(pw_sh + 128 + k0), r1b = *(const f32x4*)(pw_sh + 128 + k0 + 4);
    f32x4 r2a = *(const f32x4*)(pw_sh + 256 + k0), r2b = *(const f32x4*)(pw_sh + 256 + k0 + 4);
    f32x4 r3a = *(const f32x4*)(pw_sh + 384 + k0), r3b = *(const f32x4*)(pw_sh + 384 + k0 + 4);
    union { bf16x8 v; unsigned short u[8]; } af;
    #pragma unroll
    for (int j = 0; j < 4; ++j) {
      float z = a0 * r0a[j] + a1 * r1a[j] + a2 * r2a[j] + r3a[j];
      af.u[j] = f2bf(z * __builtin_amdgcn_rcpf(1.f + __expf(-z)));
      float z2 = a0 * r0b[j] + a1 * r1b[j] + a2 * r2b[j] + r3b[j];
      af.u[j + 4] = f2bf(z2 * __builtin_amdgcn_rcpf(1.f + __expf(-z2)));
    }
    afr[s] = af.v;
  }
  f32x4 acc[8];
  #pragma unroll
  for (int tt = 0; tt < 8; ++tt)
    #pragma unroll
    for (int r = 0; r < 4; ++r) acc[tt][r] = 0.f;
  #pragma unroll
  for (int tt = 0; tt < 8; ++tt)
    #pragma unroll
    for (int s = 0; s < 4; ++s) {
      bf16x8 b = *(const bf16x8*)(WeT + (tt * 16 + m) * 128 + s * 32 + quad * 8);
      acc[tt] = __builtin_amdgcn_mfma_f32_16x16x32_bf16(afr[s], b, acc[tt], 0, 0, 0);
    }
  #pragma unroll
  for (int tt = 0; tt < 8; ++tt) {
    int col = tt * 16 + m;
    int chunk = col >> 3, within = col & 7;
    #pragma unroll
    for (int r = 0; r < 4; ++r) {
      int le = w * 16 + quad * 4 + r;
      int p = chunk ^ (le & 7);
      ee_sh[le * 128 + p * 8 + within] = f2bf(acc[tt][r]);
    }
  }
  __syncthreads();  // tile A transpose visible

  // ---- issue tile B gathers + seattr NOW (hide under A phase 2)
  int egB = eb + 64 + le2;
  int svB = 0, dvB = 0;
  if (egB < E) { svB = ssrc[egB]; dvB = sdst[egB]; }
  bf16x8 xaB[4], xbB[4];
  #pragma unroll
  for (int j = 0; j < 4; ++j) {
    xaB[j] = *(const bf16x8*)(xl + (size_t)svB * 128 + hh * 32 + j * 8);
    xbB[j] = *(const bf16x8*)(xr + (size_t)dvB * 128 + hh * 32 + j * 8);
  }
  int eB = eb + 64 + w * 16 + m;
  float b0 = 0.f, b1 = 0.f, b2 = 0.f;
  if (eB < E) { b0 = seattr[eB * 3]; b1 = seattr[eB * 3 + 1]; b2 = seattr[eB * 3 + 2]; }
  __builtin_amdgcn_sched_barrier(0);

  // ---- tile A phase 2
  if (egA < E) {
    float sc = 0.f;
    #pragma unroll
    for (int cl = 0; cl < 4; ++cl) {
      int p = (hh * 4 + cl) ^ (le2 & 7);
      bf16x8 ev = *(const bf16x8*)(ee_sh + le2 * 128 + p * 8);
      f32x4 av0 = *(const f32x4*)(att_sh + hh * 40 + cl * 8);
      f32x4 av1 = *(const f32x4*)(att_sh + hh * 40 + cl * 8 + 4);
      #pragma unroll
      for (int q = 0; q < 8; ++q) {
        float mv = bf2f((unsigned short)ev[q])
                 + bf2f((unsigned short)xaA[cl][q])
                 + bf2f((unsigned short)xbA[cl][q]);
        mv = (mv > 0.f) ? mv : 0.2f * mv;
        float aw = (q < 4) ? av0[q] : av1[q - 4];
        sc += mv * aw;
      }
    }
    scores[egA * 4 + hh] = __expf(sc);
  }

  // ---- tile B phase 1 (register-only until transpose; overlaps freely)
  #pragma unroll
  for (int s = 0; s < 4; ++s) {
    int k0 = s * 32 + quad * 8;
    f32x4 r0a = *(const f32x4*)(pw_sh + k0),       r0b = *(const f32x4*)(pw_sh + k0 + 4);
    f32x4 r1a = *(const f32x4*)(pw_sh + 128 + k0), r1b = *(const f32x4*)(pw_sh + 128 + k0 + 4);
    f32x4 r2a = *(const f32x4*)(pw_sh + 256 + k0), r2b = *(const f32x4*)(pw_sh + 256 + k0 + 4);
    f32x4 r3a = *(const f32x4*)(pw_sh + 384 + k0), r3b = *(const f32x4*)(pw_sh + 384 + k0 + 4);
    union { bf16x8 v; unsigned short u[8]; } af;
    #pragma unroll
    for (int j = 0; j < 4; ++j) {
      float z = b0 * r0a[j] + b1 * r1a[j] + b2 * r2a[j] + r3a[j];
      af.u[j] = f2bf(z * __builtin_amdgcn_rcpf(1.f + __expf(-z)));
      float z2 = b0 * r0b[j] + b1 * r1b[j] + b2 * r2b[j] + r3b[j];
      af.u[j + 4] = f2bf(z2 * __builtin_amdgcn_rcpf(1.f + __expf(-z2)));
    }
    afr[s] = af.v;
  }
  #pragma unroll
  for (int tt = 0; tt < 8; ++tt)
    #pragma unroll
    for (int r = 0; r < 4; ++r) acc[tt][r] = 0.f;
  #pragma unroll
  for (int tt = 0; tt < 8; ++tt)
    #pragma unroll
    for (int s = 0; s < 4; ++s) {
      bf16x8 b = *(const bf16x8*)(WeT + (tt * 16 + m) * 128 + s * 32 + quad * 8);
      acc[tt] = __builtin_amdgcn_mfma_f32_16x16x32_bf16(afr[s], b, acc[tt], 0, 0, 0);
    }
  __syncthreads();  // all tile-A phase-2 ee_sh reads complete
  #pragma unroll
  for (int tt = 0; tt < 8; ++tt) {
    int col = tt * 16 + m;
    int chunk = col >> 3, within = col & 7;
    #pragma unroll
    for (int r = 0; r < 4; ++r) {
      int le = w * 16 + quad * 4 + r;
      int p = chunk ^ (le & 7);
      ee_sh[le * 128 + p * 8 + within] = f2bf(acc[tt][r]);
    }
  }
  __syncthreads();  // tile B transpose visible

  // ---- tile B phase 2
  if (egB < E) {
    float sc = 0.f;
    #pragma unroll
    for (int cl = 0; cl < 4; ++cl) {
      int p = (hh * 4 + cl) ^ (le2 & 7);
      bf16x8 ev = *(const bf16x8*)(ee_sh + le2 * 128 + p * 8);
      f32x4 av0 = *(const f32x4*)(att_sh + hh * 40 + cl * 8);
      f32x4 av1 = *(const f32x4*)(att_sh + hh * 40 + cl * 8 + 4);
      #pragma unroll
      for (int q = 0; q < 8; ++q) {
        float mv = bf2f((unsigned short)ev[q])
                 + bf2f((unsigned short)xaB[cl][q])
                 + bf2f((unsigned short)xbB[cl][q]);
        mv = (mv > 0.f) ? mv : 0.2f * mv;
        float aw = (q < 4) ? av0[q] : av1[q - 4];
        sc += mv * aw;
      }
    }
    scores[egB * 4 + hh] = __expf(sc);
  }
}

// ---------------- aggregation: w pre-exp'd, 4 cols/lane, 2 nodes/wave --------
__global__ __launch_bounds__(256) void aggregate_kernel(
    const unsigned short* __restrict__ xl, const float* __restrict__ scores,
    const int* __restrict__ off, const int* __restrict__ ssrc,
    const float* __restrict__ bias,
    const float* __restrict__ lng, const float* __restrict__ lnb,
    const float* __restrict__ h_in, float* __restrict__ h_out,
    unsigned short* __restrict__ hbf_out, int N) {
  int t = threadIdx.x;
  int wid = t >> 6, lane = t & 63;
  int half = lane >> 5, l32 = lane & 31;
  int n = blockIdx.x * 8 + wid * 2 + half;
  if (n >= N) return;
  int hh = l32 >> 3;       // 8 lanes per head group
  int col0 = l32 * 4;      // 4 consecutive cols per lane
  int p0 = off[n], p1 = off[n + 1];
  float den0 = 0.f, den1 = 0.f, den2 = 0.f, den3 = 0.f;
  float a00 = 0.f, a01 = 0.f, a02 = 0.f, a03 = 0.f;
  float a10 = 0.f, a11 = 0.f, a12 = 0.f, a13 = 0.f;
  float a20 = 0.f, a21 = 0.f, a22 = 0.f, a23 = 0.f;
  float a30 = 0.f, a31 = 0.f, a32 = 0.f, a33 = 0.f;
  int p = p0;
  for (; p + 3 < p1; p += 4) {
    float w0 = scores[p * 4 + hh];
    float w1 = scores[(p + 1) * 4 + hh];
    float w2 = scores[(p + 2) * 4 + hh];
    float w3 = scores[(p + 3) * 4 + hh];
    int s0 = ssrc[p], s1 = ssrc[p + 1], s2 = ssrc[p + 2], s3 = ssrc[p + 3];
    ushort4 x0 = *(const ushort4*)(xl + (size_t)s0 * 128 + col0);
    ushort4 x1 = *(const ushort4*)(xl + (size_t)s1 * 128 + col0);
    ushort4 x2 = *(const ushort4*)(xl + (size_t)s2 * 128 + col0);
    ushort4 x3 = *(const ushort4*)(xl + (size_t)s3 * 128 + col0);
    den0 += w0; den1 += w1; den2 += w2; den3 += w3;
    a00 += w0 * bf2f(x0.x); a01 += w0 * bf2f(x0.y); a02 += w0 * bf2f(x0.z); a03 += w0 * bf2f(x0.w);
    a10 += w1 * bf2f(x1.x); a11 += w1 * bf2f(x1.y); a12 += w1 * bf2f(x1.z); a13 += w1 * bf2f(x1.w);
    a20 += w2 * bf2f(x2.x); a21 += w2 * bf2f(x2.y); a22 += w2 * bf2f(x2.z); a23 += w2 * bf2f(x2.w);
    a30 += w3 * bf2f(x3.x); a31 += w3 * bf2f(x3.y); a32 += w3 * bf2f(x3.z); a33 += w3 * bf2f(x3.w);
  }
  for (; p < p1; ++p) {
    float w0 = scores[p * 4 + hh];
    int s0 = ssrc[p];
    ushort4 x0 = *(const ushort4*)(xl + (size_t)s0 * 128 + col0);
    den0 += w0;
    a00 += w0 * bf2f(x0.x); a01 += w0 * bf2f(x0.y); a02 += w0 * bf2f(x0.z); a03 += w0 * bf2f(x0.w);
  }
  float rden = (den0 + den1) + (den2 + den3);
  float c0 = (a00 + a10) + (a20 + a30);
  float c1 = (a01 + a11) + (a21 + a31);
  float c2 = (a02 + a12) + (a22 + a32);
  float c3 = (a03 + a13) + (a23 + a33);
  float inv = 1.f / (rden + 1e-16f);
  const float4 bb = *(const float4*)(bias + col0);
  float v0 = c0 * inv + bb.x;
  float v1 = c1 * inv + bb.y;
  float v2 = c2 * inv + bb.z;
  float v3 = c3 * inv + bb.w;
  float s1 = (v0 + v1) + (v2 + v3);
  float s2 = (v0 * v0 + v1 * v1) + (v2 * v2 + v3 * v3);
  #pragma unroll
  for (int o = 1; o < 32; o <<= 1) {  // reduce within the 32-lane half
    s1 += __shfl_xor(s1, o, 64);
    s2 += __shfl_xor(s2, o, 64);
  }
  float mean = s1 * (1.f / 128.f);
  float var = s2 * (1.f / 128.f) - mean * mean;
  float rs = rsqrtf(var + 1e-5f);
  const float4 g4 = *(const float4*)(lng + col0);
  const float4 b4 = *(const float4*)(lnb + col0);
  float y0 = (v0 - mean) * rs * g4.x + b4.x;
  float y1 = (v1 - mean) * rs * g4.y + b4.y;
  float y2 = (v2 - mean) * rs * g4.z + b4.z;
  float y3 = (v3 - mean) * rs * g4.w + b4.w;
  float o0 = y0 / (1.f + __expf(-y0));
  float o1 = y1 / (1.f + __expf(-y1));
  float o2 = y2 / (1.f + __expf(-y2));
  float o3 = y3 / (1.f + __expf(-y3));
  if (h_in) {
    const float4 hv = *(const float4*)(h_in + (size_t)n * 128 + col0);
    o0 += hv.x; o1 += hv.y; o2 += hv.z; o3 += hv.w;
  }
  float4 ov; ov.x = o0; ov.y = o1; ov.z = o2; ov.w = o3;
  *(float4*)(h_out + (size_t)n * 128 + col0) = ov;
  if (hbf_out) {
    ushort4 hb;
    hb.x = f2bf(o0); hb.y = f2bf(o1); hb.z = f2bf(o2); hb.w = f2bf(o3);
    *(ushort4*)(hbf_out + (size_t)n * 128 + col0) = hb;
  }
}

// ---------------------------------------------------------------------------
extern "C" void kernel_launch(void* const* d_in, const int* in_sizes, int n_in,
                              void* d_out, int out_size, void* d_ws, size_t ws_size,
                              hipStream_t stream) {
  const float* x       = (const float*)d_in[0];
  const int*   eidx    = (const int*)d_in[1];
  const float* eattr   = (const float*)d_in[2];
  const float* Pw      = (const float*)d_in[3];
  const float* Pb      = (const float*)d_in[4];
  const float* l0_Wl   = (const float*)d_in[5];
  const float* l0_bl   = (const float*)d_in[6];
  const float* l0_Wr   = (const float*)d_in[7];
  const float* l0_br   = (const float*)d_in[8];
  const float* l0_We   = (const float*)d_in[9];
  const float* l0_att  = (const float*)d_in[10];
  const float* l0_bias = (const float*)d_in[11];
  const float* Wl      = (const float*)d_in[12];
  const float* bl      = (const float*)d_in[13];
  const float* Wr      = (const float*)d_in[14];
  const float* br      = (const float*)d_in[15];
  const float* We      = (const float*)d_in[16];
  const float* att     = (const float*)d_in[17];
  const float* bias    = (const float*)d_in[18];
  const float* ln_g    = (const float*)d_in[19];
  const float* ln_b    = (const float*)d_in[20];
  (void)n_in; (void)out_size; (void)ws_size;

  int N = in_sizes[0] / 12;
  int E = in_sizes[2] / 3;
  const int* srcv = eidx;
  const int* dstv = eidx + E;

  char* w = (char*)d_ws;
  unsigned short* xl_bf = (unsigned short*)w; w += (size_t)N * 128 * 2;
  unsigned short* xr_bf = (unsigned short*)w; w += (size_t)N * 128 * 2;
  unsigned short* h_bf  = (unsigned short*)w; w += (size_t)N * 128 * 2;
  float* h      = (float*)w;  w += (size_t)N * 128 * 4;
  float* scores = (float*)w;  w += (size_t)E * 4 * 4;
  float* seattr = (float*)w;  w += (size_t)E * 3 * 4;
  int* ssrc   = (int*)w;      w += (size_t)E * 4;
  int* sdst   = (int*)w;      w += (size_t)E * 4;
  int* deg    = (int*)w;      w += (size_t)N * 4;
  int* off    = (int*)w;      w += (size_t)(N + 1) * 4;
  int* cursor = (int*)w;      w += (size_t)N * 4 + 12;  // keep 16B align
  unsigned short* WeT = (unsigned short*)w; w += (size_t)4 * 16384 * 2;
  unsigned short* WlT = (unsigned short*)w; w += (size_t)3 * 16384 * 2;
  unsigned short* WrT = (unsigned short*)w; w += (size_t)3 * 16384 * 2;

  // scratch for hierarchical scan: reuse scores (written only by edge_score)
  int* bsum = (int*)scores;
  int* bpre = (int*)scores + 1024;

  hipMemsetAsync(deg, 0, (size_t)N * 4, stream);
  int gE = (E + 255) / 256;
  count_kernel<<<gE, 256, 0, stream>>>(dstv, deg, E);
  int nb = (N + 1023) / 1024;
  scan_local_kernel<<<nb, 1024, 0, stream>>>(deg, off, bsum, N);
  scan_bsums_kernel<<<1, 1024, 0, stream>>>(bsum, bpre, nb, off, N);
  scan_addback_kernel<<<(N + 255) / 256, 256, 0, stream>>>(off, bpre, cursor, N);
  place_kernel<<<gE, 256, 0, stream>>>(srcv, dstv, eattr, cursor, ssrc, sdst, seattr, E);
  wt_kernel<<<10, 256, 0, stream>>>(l0_We, We, Wl, Wr, WeT, WlT, WrT);

  dim3 egrid((E + 127) / 128);
  dim3 ngrid((N + 63) / 64);
  int agrid = (N + 7) / 8;

  // layer 0 (input dim 12, no residual)
  node_proj0_kernel<<<(N * 128 + 255) / 256, 256, 0, stream>>>(
      x, l0_Wl, l0_bl, l0_Wr, l0_br, xl_bf, xr_bf, N);
  edge_score_kernel<<<egrid, 256, 0, stream>>>(
      seattr, Pw, Pb, WeT, l0_att, xl_bf, xr_bf, ssrc, sdst, scores, E);
  aggregate_kernel<<<agrid, 256, 0, stream>>>(
      xl_bf, scores, off, ssrc, l0_bias, ln_g, ln_b, nullptr, h, h_bf, N);

  // layers 1..3 (residual)
  for (int i = 0; i < 3; ++i) {
    node_proj_kernel<<<ngrid, 256, 0, stream>>>(
        h_bf, WlT + i * 16384, bl + i * 128, WrT + i * 16384, br + i * 128,
        xl_bf, xr_bf, N);
    edge_score_kernel<<<egrid, 256, 0, stream>>>(
        seattr, Pw, Pb, WeT + (i + 1) * 16384, att + i * 128,
        xl_bf, xr_bf, ssrc, sdst, scores, E);
    float* hout = (i == 2) ? (float*)d_out : h;
    unsigned short* hbfout = (i == 2) ? nullptr : h_bf;
    aggregate_kernel<<<agrid, 256, 0, stream>>>(
        xl_bf, scores, off, ssrc, bias + i * 128,
        ln_g + (i + 1) * 128, ln_b + (i + 1) * 128, h, hout, hbfout, N);
  }
}

// Round 17
// 1508.109 us; speedup vs baseline: 1.1009x; 1.1009x over previous
//
#include <hip/hip_runtime.h>
#include <hip/hip_bf16.h>

// ---------------------------------------------------------------------------
// SpatialGATEncoder: 4-layer GATv2, N=100k, E=800k, HID=128, H=4, D=32.
// Round 20 = exact revert to R18 (1523us measured best).
//  R19's 2-tile pipelined edge_score REFUTED: VGPR 64->116 halved waves/SIMD
//  (occupancy 44->22%), dur 225->260us. TLP (8 waves/SIMD) covers gather
//  latency better than intra-wave ILP here. 1-tile form is final.
// ---------------------------------------------------------------------------

using bf16x8 = __attribute__((ext_vector_type(8))) short;
using f32x4  = __attribute__((ext_vector_type(4))) float;

__device__ inline unsigned short f2bf(float x) {
  __hip_bfloat16 h = __float2bfloat16(x);
  return *reinterpret_cast<unsigned short*>(&h);
}
__device__ inline float bf2f(unsigned short u) {
  unsigned int x = ((unsigned int)u) << 16;
  return __uint_as_float(x);
}

// ---------------- CSR build ----------------
__global__ __launch_bounds__(256) void count_kernel(const int* __restrict__ dstv,
                                                    int* __restrict__ deg, int E) {
  int e = blockIdx.x * 256 + threadIdx.x;
  if (e < E) atomicAdd(&deg[dstv[e]], 1);
}

// hierarchical scan, stage 1: per-block exclusive scan of 1024 elems
__global__ __launch_bounds__(1024) void scan_local_kernel(
    const int* __restrict__ deg, int* __restrict__ off,
    int* __restrict__ bsum, int n) {
  __shared__ int wsum[16];
  int t = threadIdx.x;
  int lane = t & 63, wid = t >> 6;
  int i = blockIdx.x * 1024 + t;
  int v = (i < n) ? deg[i] : 0;
  int x = v;
  #pragma unroll
  for (int o = 1; o < 64; o <<= 1) {
    int y = __shfl_up(x, o, 64);
    if (lane >= o) x += y;
  }
  if (lane == 63) wsum[wid] = x;
  __syncthreads();
  if (wid == 0) {
    int w = (lane < 16) ? wsum[lane] : 0;
    #pragma unroll
    for (int o = 1; o < 16; o <<= 1) {
      int y = __shfl_up(w, o, 64);
      if (lane >= o) w += y;
    }
    if (lane < 16) wsum[lane] = w;
  }
  __syncthreads();
  int wbase = (wid == 0) ? 0 : wsum[wid - 1];
  if (i < n) off[i] = wbase + (x - v);
  if (t == 0) bsum[blockIdx.x] = wsum[15];
}

// stage 2: single-block scan of the <=1024 block sums; writes off[n] = total
__global__ __launch_bounds__(1024) void scan_bsums_kernel(
    const int* __restrict__ bsum, int* __restrict__ bpre,
    int nb, int* __restrict__ off, int n) {
  __shared__ int wsum[16];
  int t = threadIdx.x;
  int lane = t & 63, wid = t >> 6;
  int v = (t < nb) ? bsum[t] : 0;
  int x = v;
  #pragma unroll
  for (int o = 1; o < 64; o <<= 1) {
    int y = __shfl_up(x, o, 64);
    if (lane >= o) x += y;
  }
  if (lane == 63) wsum[wid] = x;
  __syncthreads();
  if (wid == 0) {
    int w = (lane < 16) ? wsum[lane] : 0;
    #pragma unroll
    for (int o = 1; o < 16; o <<= 1) {
      int y = __shfl_up(w, o, 64);
      if (lane >= o) w += y;
    }
    if (lane < 16) wsum[lane] = w;
  }
  __syncthreads();
  int wbase = (wid == 0) ? 0 : wsum[wid - 1];
  if (t < nb) bpre[t] = wbase + (x - v);
  if (t == 0) off[n] = wsum[15];
}

// stage 3: add block prefix back; copy to cursor
__global__ __launch_bounds__(256) void scan_addback_kernel(
    int* __restrict__ off, const int* __restrict__ bpre,
    int* __restrict__ cursor, int n) {
  int i = blockIdx.x * 256 + threadIdx.x;
  if (i < n) {
    int v = off[i] + bpre[i >> 10];
    off[i] = v;
    cursor[i] = v;
  }
}

// sort edges by dst: ssrc/sdst/seattr in segment order
__global__ __launch_bounds__(256) void place_kernel(const int* __restrict__ srcv,
                                                    const int* __restrict__ dstv,
                                                    const float* __restrict__ eattr,
                                                    int* __restrict__ cursor,
                                                    int* __restrict__ ssrc,
                                                    int* __restrict__ sdst,
                                                    float* __restrict__ seattr, int E) {
  int e = blockIdx.x * 256 + threadIdx.x;
  if (e < E) {
    int d = dstv[e];
    int p = atomicAdd(&cursor[d], 1);
    ssrc[p] = srcv[e];
    sdst[p] = d;
    seattr[p * 3 + 0] = eattr[e * 3 + 0];
    seattr[p * 3 + 1] = eattr[e * 3 + 1];
    seattr[p * 3 + 2] = eattr[e * 3 + 2];
  }
}

// ---------------- weight transpose f32 -> bf16, WT[n][k] = W[k][n] ----------------
// 10 blocks: 0..3 We (l0 + 3), 4..6 Wl, 7..9 Wr
__global__ __launch_bounds__(256) void wt_kernel(
    const float* __restrict__ l0_We, const float* __restrict__ We,
    const float* __restrict__ Wl, const float* __restrict__ Wr,
    unsigned short* __restrict__ WeT, unsigned short* __restrict__ WlT,
    unsigned short* __restrict__ WrT) {
  int b = blockIdx.x, t = threadIdx.x;
  const float* src;
  unsigned short* dst;
  if (b == 0)      { src = l0_We;              dst = WeT; }
  else if (b < 4)  { src = We + (b - 1) * 16384; dst = WeT + b * 16384; }
  else if (b < 7)  { src = Wl + (b - 4) * 16384; dst = WlT + (b - 4) * 16384; }
  else             { src = Wr + (b - 7) * 16384; dst = WrT + (b - 7) * 16384; }
  int n = t >> 1, k0 = (t & 1) * 64;
  #pragma unroll
  for (int k = 0; k < 64; ++k)
    dst[n * 128 + k0 + k] = f2bf(src[(k0 + k) * 128 + n]);
}

// ---------------- layer-0 node projection (K = 12) -> bf16 ----------------
__global__ __launch_bounds__(256) void node_proj0_kernel(
    const float* __restrict__ x,
    const float* __restrict__ Wl, const float* __restrict__ bl,
    const float* __restrict__ Wr, const float* __restrict__ br,
    unsigned short* __restrict__ xl, unsigned short* __restrict__ xr, int N) {
  int idx = blockIdx.x * 256 + threadIdx.x;
  int node = idx >> 7, col = idx & 127;
  if (node >= N) return;
  float al = bl[col], ar = br[col];
  const float* xrow = x + node * 12;
  #pragma unroll
  for (int k = 0; k < 12; ++k) {
    float xv = xrow[k];
    al += xv * Wl[k * 128 + col];
    ar += xv * Wr[k * 128 + col];
  }
  xl[idx] = f2bf(al);
  xr[idx] = f2bf(ar);
}

// ---------------- node projection MFMA: xl = h@Wl+bl, xr = h@Wr+br (bf16) ----------------
__global__ __launch_bounds__(256) void node_proj_kernel(
    const unsigned short* __restrict__ hbf,
    const unsigned short* __restrict__ WlT, const float* __restrict__ bl,
    const unsigned short* __restrict__ WrT, const float* __restrict__ br,
    unsigned short* __restrict__ xl, unsigned short* __restrict__ xr, int N) {
  __shared__ unsigned short A_sh[64 * 136];
  int t = threadIdx.x;
  int nb = blockIdx.x * 64;
  #pragma unroll
  for (int it = 0; it < 4; ++it) {
    int idx = it * 256 + t;
    int row = idx >> 4, chunk = idx & 15;
    int ng = nb + row;
    float4 v = make_float4(0.f, 0.f, 0.f, 0.f);
    if (ng < N) v = *(const float4*)(hbf + ng * 128 + chunk * 8);
    *(float4*)(A_sh + row * 136 + chunk * 8) = v;
  }
  __syncthreads();
  int lane = t & 63, w = t >> 6;
  int m = lane & 15, quad = lane >> 4;
  bf16x8 afr[4];
  #pragma unroll
  for (int s = 0; s < 4; ++s)
    afr[s] = *(const bf16x8*)(A_sh + (w * 16 + m) * 136 + s * 32 + quad * 8);
  #pragma unroll
  for (int part = 0; part < 2; ++part) {
    const unsigned short* Bt = part ? WrT : WlT;
    const float* bias = part ? br : bl;
    unsigned short* out = part ? xr : xl;
    f32x4 acc[8];
    #pragma unroll
    for (int tt = 0; tt < 8; ++tt)
      #pragma unroll
      for (int r = 0; r < 4; ++r) acc[tt][r] = 0.f;
    #pragma unroll
    for (int tt = 0; tt < 8; ++tt)
      #pragma unroll
      for (int s = 0; s < 4; ++s) {
        bf16x8 b = *(const bf16x8*)(Bt + (tt * 16 + m) * 128 + s * 32 + quad * 8);
        acc[tt] = __builtin_amdgcn_mfma_f32_16x16x32_bf16(afr[s], b, acc[tt], 0, 0, 0);
      }
    #pragma unroll
    for (int tt = 0; tt < 8; ++tt) {
      int col = tt * 16 + m;
      float bv = bias[col];
      #pragma unroll
      for (int r = 0; r < 4; ++r) {
        int ng = nb + w * 16 + quad * 4 + r;
        if (ng < N) out[ng * 128 + col] = f2bf(acc[tt][r] + bv);
      }
    }
  }
}

// ---------------- fused edge-score kernel (T14 hoist + pw_sh staging) --------
// scores[] stores w = exp(sc) -- exp runs here where VALU is idle.
__global__ __launch_bounds__(256) void edge_score_kernel(
    const float* __restrict__ seattr,  // E x 3 (sorted)
    const float* __restrict__ Pw,      // 3 x 128
    const float* __restrict__ Pb,      // 128
    const unsigned short* __restrict__ WeT,  // 128 x 128 bf16 [n][k]
    const float* __restrict__ attw,    // 128
    const unsigned short* __restrict__ xl, const unsigned short* __restrict__ xr,
    const int* __restrict__ ssrc, const int* __restrict__ sdst,
    float* __restrict__ scores, int E) {
  __shared__ unsigned short ee_sh[64 * 128];  // 16 KB, XOR-swizzled 16B chunks
  __shared__ float att_sh[4 * 40];            // head-major, stride 40
  __shared__ float pw_sh[512];                // Pw rows 0..2 then Pb
  int t = threadIdx.x;
  int eb = blockIdx.x * 64;
  int lane = t & 63, w = t >> 6;
  int m = lane & 15, quad = lane >> 4;

  if (t < 128) att_sh[(t >> 5) * 40 + (t & 31)] = attw[t];
  for (int i = t; i < 512; i += 256) pw_sh[i] = (i < 384) ? Pw[i] : Pb[i - 384];

  // T14 hoist: issue phase-2 gathers now; consumed after the transpose barrier.
  int le2 = t >> 2, hh = t & 3;
  int eg = eb + le2;
  int sv = 0, dv = 0;
  if (eg < E) { sv = ssrc[eg]; dv = sdst[eg]; }
  bf16x8 xa[4], xb[4];
  #pragma unroll
  for (int j = 0; j < 4; ++j) {
    xa[j] = *(const bf16x8*)(xl + (size_t)sv * 128 + hh * 32 + j * 8);
    xb[j] = *(const bf16x8*)(xr + (size_t)dv * 128 + hh * 32 + j * 8);
  }
  __builtin_amdgcn_sched_barrier(0);  // pin: gathers issued before phase 1
  __syncthreads();  // pw_sh / att_sh ready

  // phase 1: A-fragment (edge e = eb + w*16 + m) from pw_sh (f32x4 reads)
  int e = eb + w * 16 + m;
  float ea0 = 0.f, ea1 = 0.f, ea2 = 0.f;
  if (e < E) { ea0 = seattr[e * 3]; ea1 = seattr[e * 3 + 1]; ea2 = seattr[e * 3 + 2]; }
  bf16x8 afr[4];
  #pragma unroll
  for (int s = 0; s < 4; ++s) {
    int k0 = s * 32 + quad * 8;
    f32x4 r0a = *(const f32x4*)(pw_sh + k0),       r0b = *(const f32x4*)(pw_sh + k0 + 4);
    f32x4 r1a = *(const f32x4*)(pw_sh + 128 + k0), r1b = *(const f32x4*)(pw_sh + 128 + k0 + 4);
    f32x4 r2a = *(const f32x4*)(pw_sh + 256 + k0), r2b = *(const f32x4*)(pw_sh + 256 + k0 + 4);
    f32x4 r3a = *(const f32x4*)(pw_sh + 384 + k0), r3b = *(const f32x4*)(pw_sh + 384 + k0 + 4);
    union { bf16x8 v; unsigned short u[8]; } af;
    #pragma unroll
    for (int j = 0; j < 4; ++j) {
      float z = ea0 * r0a[j] + ea1 * r1a[j] + ea2 * r2a[j] + r3a[j];
      af.u[j] = f2bf(z * __builtin_amdgcn_rcpf(1.f + __expf(-z)));
      float z2 = ea0 * r0b[j] + ea1 * r1b[j] + ea2 * r2b[j] + r3b[j];
      af.u[j + 4] = f2bf(z2 * __builtin_amdgcn_rcpf(1.f + __expf(-z2)));
    }
    afr[s] = af.v;
  }

  f32x4 acc[8];
  #pragma unroll
  for (int tt = 0; tt < 8; ++tt)
    #pragma unroll
    for (int r = 0; r < 4; ++r) acc[tt][r] = 0.f;
  #pragma unroll
  for (int tt = 0; tt < 8; ++tt)
    #pragma unroll
    for (int s = 0; s < 4; ++s) {
      bf16x8 b = *(const bf16x8*)(WeT + (tt * 16 + m) * 128 + s * 32 + quad * 8);
      acc[tt] = __builtin_amdgcn_mfma_f32_16x16x32_bf16(afr[s], b, acc[tt], 0, 0, 0);
    }

  // ee -> LDS (bf16, XOR-swizzled 16B chunks)
  #pragma unroll
  for (int tt = 0; tt < 8; ++tt) {
    int col = tt * 16 + m;
    int chunk = col >> 3, within = col & 7;
    #pragma unroll
    for (int r = 0; r < 4; ++r) {
      int le = w * 16 + quad * 4 + r;
      int p = chunk ^ (le & 7);
      ee_sh[le * 128 + p * 8 + within] = f2bf(acc[tt][r]);
    }
  }
  __syncthreads();

  // phase 2: thread t -> local edge t>>2, head t&3 (gathers in regs)
  if (eg < E) {
    float sc = 0.f;
    #pragma unroll
    for (int cl = 0; cl < 4; ++cl) {
      int p = (hh * 4 + cl) ^ (le2 & 7);
      bf16x8 ev = *(const bf16x8*)(ee_sh + le2 * 128 + p * 8);
      f32x4 av0 = *(const f32x4*)(att_sh + hh * 40 + cl * 8);
      f32x4 av1 = *(const f32x4*)(att_sh + hh * 40 + cl * 8 + 4);
      #pragma unroll
      for (int q = 0; q < 8; ++q) {
        float mv = bf2f((unsigned short)ev[q])
                 + bf2f((unsigned short)xa[cl][q])
                 + bf2f((unsigned short)xb[cl][q]);
        mv = (mv > 0.f) ? mv : 0.2f * mv;
        float aw = (q < 4) ? av0[q] : av1[q - 4];
        sc += mv * aw;
      }
    }
    scores[eg * 4 + hh] = __expf(sc);  // w stored directly (max-free softmax)
  }
}

// ---------------- aggregation: w pre-exp'd, 4 cols/lane, 2 nodes/wave --------
__global__ __launch_bounds__(256) void aggregate_kernel(
    const unsigned short* __restrict__ xl, const float* __restrict__ scores,
    const int* __restrict__ off, const int* __restrict__ ssrc,
    const float* __restrict__ bias,
    const float* __restrict__ lng, const float* __restrict__ lnb,
    const float* __restrict__ h_in, float* __restrict__ h_out,
    unsigned short* __restrict__ hbf_out, int N) {
  int t = threadIdx.x;
  int wid = t >> 6, lane = t & 63;
  int half = lane >> 5, l32 = lane & 31;
  int n = blockIdx.x * 8 + wid * 2 + half;
  if (n >= N) return;
  int hh = l32 >> 3;       // 8 lanes per head group
  int col0 = l32 * 4;      // 4 consecutive cols per lane
  int p0 = off[n], p1 = off[n + 1];
  float den0 = 0.f, den1 = 0.f, den2 = 0.f, den3 = 0.f;
  float a00 = 0.f, a01 = 0.f, a02 = 0.f, a03 = 0.f;
  float a10 = 0.f, a11 = 0.f, a12 = 0.f, a13 = 0.f;
  float a20 = 0.f, a21 = 0.f, a22 = 0.f, a23 = 0.f;
  float a30 = 0.f, a31 = 0.f, a32 = 0.f, a33 = 0.f;
  int p = p0;
  for (; p + 3 < p1; p += 4) {
    float w0 = scores[p * 4 + hh];
    float w1 = scores[(p + 1) * 4 + hh];
    float w2 = scores[(p + 2) * 4 + hh];
    float w3 = scores[(p + 3) * 4 + hh];
    int s0 = ssrc[p], s1 = ssrc[p + 1], s2 = ssrc[p + 2], s3 = ssrc[p + 3];
    ushort4 x0 = *(const ushort4*)(xl + (size_t)s0 * 128 + col0);
    ushort4 x1 = *(const ushort4*)(xl + (size_t)s1 * 128 + col0);
    ushort4 x2 = *(const ushort4*)(xl + (size_t)s2 * 128 + col0);
    ushort4 x3 = *(const ushort4*)(xl + (size_t)s3 * 128 + col0);
    den0 += w0; den1 += w1; den2 += w2; den3 += w3;
    a00 += w0 * bf2f(x0.x); a01 += w0 * bf2f(x0.y); a02 += w0 * bf2f(x0.z); a03 += w0 * bf2f(x0.w);
    a10 += w1 * bf2f(x1.x); a11 += w1 * bf2f(x1.y); a12 += w1 * bf2f(x1.z); a13 += w1 * bf2f(x1.w);
    a20 += w2 * bf2f(x2.x); a21 += w2 * bf2f(x2.y); a22 += w2 * bf2f(x2.z); a23 += w2 * bf2f(x2.w);
    a30 += w3 * bf2f(x3.x); a31 += w3 * bf2f(x3.y); a32 += w3 * bf2f(x3.z); a33 += w3 * bf2f(x3.w);
  }
  for (; p < p1; ++p) {
    float w0 = scores[p * 4 + hh];
    int s0 = ssrc[p];
    ushort4 x0 = *(const ushort4*)(xl + (size_t)s0 * 128 + col0);
    den0 += w0;
    a00 += w0 * bf2f(x0.x); a01 += w0 * bf2f(x0.y); a02 += w0 * bf2f(x0.z); a03 += w0 * bf2f(x0.w);
  }
  float rden = (den0 + den1) + (den2 + den3);
  float c0 = (a00 + a10) + (a20 + a30);
  float c1 = (a01 + a11) + (a21 + a31);
  float c2 = (a02 + a12) + (a22 + a32);
  float c3 = (a03 + a13) + (a23 + a33);
  float inv = 1.f / (rden + 1e-16f);
  const float4 bb = *(const float4*)(bias + col0);
  float v0 = c0 * inv + bb.x;
  float v1 = c1 * inv + bb.y;
  float v2 = c2 * inv + bb.z;
  float v3 = c3 * inv + bb.w;
  float s1 = (v0 + v1) + (v2 + v3);
  float s2 = (v0 * v0 + v1 * v1) + (v2 * v2 + v3 * v3);
  #pragma unroll
  for (int o = 1; o < 32; o <<= 1) {  // reduce within the 32-lane half
    s1 += __shfl_xor(s1, o, 64);
    s2 += __shfl_xor(s2, o, 64);
  }
  float mean = s1 * (1.f / 128.f);
  float var = s2 * (1.f / 128.f) - mean * mean;
  float rs = rsqrtf(var + 1e-5f);
  const float4 g4 = *(const float4*)(lng + col0);
  const float4 b4 = *(const float4*)(lnb + col0);
  float y0 = (v0 - mean) * rs * g4.x + b4.x;
  float y1 = (v1 - mean) * rs * g4.y + b4.y;
  float y2 = (v2 - mean) * rs * g4.z + b4.z;
  float y3 = (v3 - mean) * rs * g4.w + b4.w;
  float o0 = y0 / (1.f + __expf(-y0));
  float o1 = y1 / (1.f + __expf(-y1));
  float o2 = y2 / (1.f + __expf(-y2));
  float o3 = y3 / (1.f + __expf(-y3));
  if (h_in) {
    const float4 hv = *(const float4*)(h_in + (size_t)n * 128 + col0);
    o0 += hv.x; o1 += hv.y; o2 += hv.z; o3 += hv.w;
  }
  float4 ov; ov.x = o0; ov.y = o1; ov.z = o2; ov.w = o3;
  *(float4*)(h_out + (size_t)n * 128 + col0) = ov;
  if (hbf_out) {
    ushort4 hb;
    hb.x = f2bf(o0); hb.y = f2bf(o1); hb.z = f2bf(o2); hb.w = f2bf(o3);
    *(ushort4*)(hbf_out + (size_t)n * 128 + col0) = hb;
  }
}

// ---------------------------------------------------------------------------
extern "C" void kernel_launch(void* const* d_in, const int* in_sizes, int n_in,
                              void* d_out, int out_size, void* d_ws, size_t ws_size,
                              hipStream_t stream) {
  const float* x       = (const float*)d_in[0];
  const int*   eidx    = (const int*)d_in[1];
  const float* eattr   = (const float*)d_in[2];
  const float* Pw      = (const float*)d_in[3];
  const float* Pb      = (const float*)d_in[4];
  const float* l0_Wl   = (const float*)d_in[5];
  const float* l0_bl   = (const float*)d_in[6];
  const float* l0_Wr   = (const float*)d_in[7];
  const float* l0_br   = (const float*)d_in[8];
  const float* l0_We   = (const float*)d_in[9];
  const float* l0_att  = (const float*)d_in[10];
  const float* l0_bias = (const float*)d_in[11];
  const float* Wl      = (const float*)d_in[12];
  const float* bl      = (const float*)d_in[13];
  const float* Wr      = (const float*)d_in[14];
  const float* br      = (const float*)d_in[15];
  const float* We      = (const float*)d_in[16];
  const float* att     = (const float*)d_in[17];
  const float* bias    = (const float*)d_in[18];
  const float* ln_g    = (const float*)d_in[19];
  const float* ln_b    = (const float*)d_in[20];
  (void)n_in; (void)out_size; (void)ws_size;

  int N = in_sizes[0] / 12;
  int E = in_sizes[2] / 3;
  const int* srcv = eidx;
  const int* dstv = eidx + E;

  char* w = (char*)d_ws;
  unsigned short* xl_bf = (unsigned short*)w; w += (size_t)N * 128 * 2;
  unsigned short* xr_bf = (unsigned short*)w; w += (size_t)N * 128 * 2;
  unsigned short* h_bf  = (unsigned short*)w; w += (size_t)N * 128 * 2;
  float* h      = (float*)w;  w += (size_t)N * 128 * 4;
  float* scores = (float*)w;  w += (size_t)E * 4 * 4;
  float* seattr = (float*)w;  w += (size_t)E * 3 * 4;
  int* ssrc   = (int*)w;      w += (size_t)E * 4;
  int* sdst   = (int*)w;      w += (size_t)E * 4;
  int* deg    = (int*)w;      w += (size_t)N * 4;
  int* off    = (int*)w;      w += (size_t)(N + 1) * 4;
  int* cursor = (int*)w;      w += (size_t)N * 4 + 12;  // keep 16B align
  unsigned short* WeT = (unsigned short*)w; w += (size_t)4 * 16384 * 2;
  unsigned short* WlT = (unsigned short*)w; w += (size_t)3 * 16384 * 2;
  unsigned short* WrT = (unsigned short*)w; w += (size_t)3 * 16384 * 2;

  // scratch for hierarchical scan: reuse scores (written only by edge_score)
  int* bsum = (int*)scores;
  int* bpre = (int*)scores + 1024;

  hipMemsetAsync(deg, 0, (size_t)N * 4, stream);
  int gE = (E + 255) / 256;
  count_kernel<<<gE, 256, 0, stream>>>(dstv, deg, E);
  int nb = (N + 1023) / 1024;
  scan_local_kernel<<<nb, 1024, 0, stream>>>(deg, off, bsum, N);
  scan_bsums_kernel<<<1, 1024, 0, stream>>>(bsum, bpre, nb, off, N);
  scan_addback_kernel<<<(N + 255) / 256, 256, 0, stream>>>(off, bpre, cursor, N);
  place_kernel<<<gE, 256, 0, stream>>>(srcv, dstv, eattr, cursor, ssrc, sdst, seattr, E);
  wt_kernel<<<10, 256, 0, stream>>>(l0_We, We, Wl, Wr, WeT, WlT, WrT);

  dim3 egrid((E + 63) / 64);
  dim3 ngrid((N + 63) / 64);
  int agrid = (N + 7) / 8;

  // layer 0 (input dim 12, no residual)
  node_proj0_kernel<<<(N * 128 + 255) / 256, 256, 0, stream>>>(
      x, l0_Wl, l0_bl, l0_Wr, l0_br, xl_bf, xr_bf, N);
  edge_score_kernel<<<egrid, 256, 0, stream>>>(
      seattr, Pw, Pb, WeT, l0_att, xl_bf, xr_bf, ssrc, sdst, scores, E);
  aggregate_kernel<<<agrid, 256, 0, stream>>>(
      xl_bf, scores, off, ssrc, l0_bias, ln_g, ln_b, nullptr, h, h_bf, N);

  // layers 1..3 (residual)
  for (int i = 0; i < 3; ++i) {
    node_proj_kernel<<<ngrid, 256, 0, stream>>>(
        h_bf, WlT + i * 16384, bl + i * 128, WrT + i * 16384, br + i * 128,
        xl_bf, xr_bf, N);
    edge_score_kernel<<<egrid, 256, 0, stream>>>(
        seattr, Pw, Pb, WeT + (i + 1) * 16384, att + i * 128,
        xl_bf, xr_bf, ssrc, sdst, scores, E);
    float* hout = (i == 2) ? (float*)d_out : h;
    unsigned short* hbfout = (i == 2) ? nullptr : h_bf;
    aggregate_kernel<<<agrid, 256, 0, stream>>>(
        xl_bf, scores, off, ssrc, bias + i * 128,
        ln_g + (i + 1) * 128, ln_b + (i + 1) * 128, h, hout, hbfout, N);
  }
}